// Round 3
// baseline (671.243 us; speedup 1.0000x reference)
//
#include <hip/hip_runtime.h>
#include <hip/hip_bf16.h>

#define N_TOK 4096
#define C_IN  128
#define SCALE 0.17677669529663687f  // 32^-0.5

// ---------------------------------------------------------------------------
// Kernel A: qkv[b][o][i] = sum_c w_qkv[o][c] * x[b][c][i]   (q rows pre-scaled)
// grid (N_TOK/256, 384/16, 2), block 256
// ---------------------------------------------------------------------------
__global__ void qkv_proj(const float* __restrict__ x, const float* __restrict__ w,
                         float* __restrict__ qkv) {
    int i  = blockIdx.x * 256 + threadIdx.x;
    int o0 = blockIdx.y * 16;
    int b  = blockIdx.z;
    __shared__ float wl[16][C_IN];
    for (int t = threadIdx.x; t < 16 * C_IN; t += 256)
        wl[t >> 7][t & 127] = w[(o0 + (t >> 7)) * C_IN + (t & 127)];
    __syncthreads();
    const float* xp = x + (size_t)b * C_IN * N_TOK + i;
    float acc[16];
#pragma unroll
    for (int r = 0; r < 16; ++r) acc[r] = 0.f;
#pragma unroll 4
    for (int c = 0; c < C_IN; ++c) {
        float xv = xp[(size_t)c * N_TOK];
#pragma unroll
        for (int r = 0; r < 16; ++r) acc[r] += wl[r][c] * xv;
    }
    float sc = (o0 < 128) ? SCALE : 1.0f;  // q rows are o in [0,128)
#pragma unroll
    for (int r = 0; r < 16; ++r)
        qkv[((size_t)b * 384 + o0 + r) * N_TOK + i] = acc[r] * sc;
}

// ---------------------------------------------------------------------------
// Kernel B: flash attention (no-max softmax: exp(s) can't overflow, |s| << 80)
// grid (N_TOK/64, 8=b*h), block 256 = 4 waves; wave w handles keys
// [w*1024, w*1024+1024) for the same 64 queries; partials combined in LDS.
// ---------------------------------------------------------------------------
__global__ void __launch_bounds__(256, 2)
attn_fa(const float* __restrict__ qkv, float* __restrict__ ao) {
    int bh   = blockIdx.y;
    int b    = bh >> 2, h = bh & 3;
    int lane = threadIdx.x & 63;
    int wv   = threadIdx.x >> 6;
    int qi   = blockIdx.x * 64 + lane;

    const float* qp = qkv + ((size_t)b * 384 + h * 32) * N_TOK;
    const float* kp = qp + (size_t)128 * N_TOK;
    const float* vp = qp + (size_t)256 * N_TOK;

    float q[32], o[32];
#pragma unroll
    for (int d = 0; d < 32; ++d) { q[d] = qp[(size_t)d * N_TOK + qi]; o[d] = 0.f; }
    float l = 0.f;

    __shared__ float kt[4][32][64];
    __shared__ float vt[4][32][64];

    int j_beg = wv * 1024;
    for (int j0 = j_beg; j0 < j_beg + 1024; j0 += 64) {
#pragma unroll
        for (int d = 0; d < 32; ++d) {
            kt[wv][d][lane] = kp[(size_t)d * N_TOK + j0 + lane];
            vt[wv][d][lane] = vp[(size_t)d * N_TOK + j0 + lane];
        }
        __syncthreads();  // waves only touch their own slice; sync is belt+braces
        for (int j = 0; j < 64; j += 4) {
            float4 s = {0.f, 0.f, 0.f, 0.f};
#pragma unroll
            for (int d = 0; d < 32; ++d) {
                float4 kv = *(const float4*)&kt[wv][d][j];
                s.x += q[d] * kv.x; s.y += q[d] * kv.y;
                s.z += q[d] * kv.z; s.w += q[d] * kv.w;
            }
            float4 p;
            p.x = __expf(s.x); p.y = __expf(s.y);
            p.z = __expf(s.z); p.w = __expf(s.w);
            l += (p.x + p.y) + (p.z + p.w);
#pragma unroll
            for (int d = 0; d < 32; ++d) {
                float4 vv = *(const float4*)&vt[wv][d][j];
                o[d] += p.x * vv.x + p.y * vv.y + p.z * vv.z + p.w * vv.w;
            }
        }
        __syncthreads();
    }

    // -------- intra-block combine over the 4 key-splits (reuse LDS) --------
    __syncthreads();
    float* osh = &kt[0][0][0];  // [4][32][64] partial o
    float* lsh = &vt[0][0][0];  // [4][64]     partial l
#pragma unroll
    for (int d = 0; d < 32; ++d) osh[((size_t)wv * 32 + d) * 64 + lane] = o[d];
    lsh[wv * 64 + lane] = l;
    __syncthreads();
    float lt  = lsh[lane] + lsh[64 + lane] + lsh[128 + lane] + lsh[192 + lane];
    float inv = 1.f / lt;
#pragma unroll
    for (int r = 0; r < 8; ++r) {
        int d = wv * 8 + r;
        float s = osh[(size_t)d * 64 + lane] + osh[((size_t)32 + d) * 64 + lane] +
                  osh[((size_t)64 + d) * 64 + lane] + osh[((size_t)96 + d) * 64 + lane];
        ao[((size_t)b * 128 + h * 32 + d) * N_TOK + qi] = s * inv;
    }
}

// ---------------------------------------------------------------------------
// Kernel C: out[b][o][i] = sum_c w_out[o][c]*ao[b][c][i] + b_out[o] + x[b][o][i]
// grid (N_TOK/256, 128/16, 2), block 256
// ---------------------------------------------------------------------------
__global__ void out_proj(const float* __restrict__ ao, const float* __restrict__ w,
                         const float* __restrict__ bias, const float* __restrict__ x,
                         float* __restrict__ out) {
    int i  = blockIdx.x * 256 + threadIdx.x;
    int o0 = blockIdx.y * 16;
    int b  = blockIdx.z;
    __shared__ float wl[16][C_IN];
    for (int t = threadIdx.x; t < 16 * C_IN; t += 256)
        wl[t >> 7][t & 127] = w[(o0 + (t >> 7)) * C_IN + (t & 127)];
    __syncthreads();
    const float* ap = ao + (size_t)b * C_IN * N_TOK + i;
    float acc[16];
#pragma unroll
    for (int r = 0; r < 16; ++r) acc[r] = 0.f;
#pragma unroll 4
    for (int c = 0; c < C_IN; ++c) {
        float av = ap[(size_t)c * N_TOK];
#pragma unroll
        for (int r = 0; r < 16; ++r) acc[r] += wl[r][c] * av;
    }
#pragma unroll
    for (int r = 0; r < 16; ++r) {
        int oc = o0 + r;
        float res = x[((size_t)b * 128 + oc) * N_TOK + i];
        out[((size_t)b * 128 + oc) * N_TOK + i] = acc[r] + bias[oc] + res;
    }
}

// ---------------------------------------------------------------------------
extern "C" void kernel_launch(void* const* d_in, const int* in_sizes, int n_in,
                              void* d_out, int out_size, void* d_ws, size_t ws_size,
                              hipStream_t stream) {
    const float* x     = (const float*)d_in[0];
    const float* w_qkv = (const float*)d_in[1];
    const float* w_out = (const float*)d_in[2];
    const float* b_out = (const float*)d_in[3];
    float* out = (float*)d_out;

    float* qkv = (float*)d_ws;                         // [2][384][4096] f32
    float* ao  = qkv + (size_t)2 * 384 * N_TOK;        // [2][128][4096] f32

    qkv_proj<<<dim3(N_TOK / 256, 384 / 16, 2), 256, 0, stream>>>(x, w_qkv, qkv);
    attn_fa <<<dim3(N_TOK / 64, 8), 256, 0, stream>>>(qkv, ao);
    out_proj<<<dim3(N_TOK / 256, 128 / 16, 2), 256, 0, stream>>>(ao, w_out, b_out, x, out);
}

// Round 5
// 216.213 us; speedup vs baseline: 3.1045x; 3.1045x over previous
//
#include <hip/hip_runtime.h>
#include <hip/hip_bf16.h>

typedef __hip_bfloat16 bf16;
typedef float    f32x16 __attribute__((ext_vector_type(16)));
typedef __bf16   bf16x8 __attribute__((ext_vector_type(8)));
typedef unsigned uint4v __attribute__((ext_vector_type(4)));
typedef int      i32x2  __attribute__((ext_vector_type(2)));

#define N_TOK 4096
#define SCALE 0.17677669529663687f  // 32^-0.5

__device__ __forceinline__ bf16x8 ld8(const bf16* p) {
    return *(const bf16x8*)p;
}
// pack two f32 -> one dword of 2 bf16 (lo = a, hi = b); native __bf16 casts are
// trivially copyable and the compiler fuses to v_cvt_pk_bf16_f32.
__device__ __forceinline__ unsigned pack2(float a, float b) {
    unsigned short ua = __builtin_bit_cast(unsigned short, (__bf16)a);
    unsigned short ub = __builtin_bit_cast(unsigned short, (__bf16)b);
    return (unsigned)ua | ((unsigned)ub << 16);
}

// ---------------------------------------------------------------------------
// Kernel A: qkv projection, f32 compute, bf16 outputs in MFMA layouts:
//   q_t[bh][tok][d] (scaled), k_t[bh][tok][d], v[bh][d][tok]
// grid (16, 12, 2), block 256; W rows read via uniform (scalar) loads.
// ---------------------------------------------------------------------------
__global__ void __launch_bounds__(256)
qkv_proj(const float* __restrict__ x, const float* __restrict__ w,
         bf16* __restrict__ qt, bf16* __restrict__ kt, bf16* __restrict__ vt) {
    int i  = blockIdx.x * 256 + threadIdx.x;
    int o0 = blockIdx.y * 32;
    int b  = blockIdx.z;
    const float* xp = x + (size_t)b * (128 * N_TOK) + i;
    const float* wp = w + (size_t)o0 * 128;
    float acc[32];
#pragma unroll
    for (int r = 0; r < 32; ++r) acc[r] = 0.f;
    for (int c = 0; c < 128; ++c) {
        float xv = xp[(size_t)c * N_TOK];
#pragma unroll
        for (int r = 0; r < 32; ++r) acc[r] = fmaf(wp[r * 128 + c], xv, acc[r]);
    }
    if (o0 < 256) {  // q or k: transposed [tok][d] bf16, 64B/thread contiguous
        bf16* base = (o0 < 128) ? qt : kt;
        int   h    = (o0 & 127) >> 5;
        float sc   = (o0 < 128) ? SCALE : 1.0f;
        unsigned wb[16];
#pragma unroll
        for (int k = 0; k < 16; ++k) wb[k] = pack2(acc[2 * k] * sc, acc[2 * k + 1] * sc);
        uint4v* dst = (uint4v*)(base + ((size_t)(b * 4 + h) * N_TOK + i) * 32);
#pragma unroll
        for (int t = 0; t < 4; ++t)
            dst[t] = (uint4v){wb[4 * t], wb[4 * t + 1], wb[4 * t + 2], wb[4 * t + 3]};
    } else {         // v: row-major [d][tok] bf16 (coalesced per-row stores)
        int od = o0 - 256;
#pragma unroll
        for (int r = 0; r < 32; ++r)
            vt[((size_t)b * 128 + od + r) * N_TOK + i] = __float2bfloat16(acc[r]);
    }
}

// ---------------------------------------------------------------------------
// Kernel B: MFMA flash attention, swapped operands (S^T = K^T.Q), no-max
// softmax (|s| << 80 so exp can't overflow), P->PV via cvt_pk + permlane32_swap.
// 1 wave = 32 queries, all 4096 keys. No LDS, no barriers.
// grid (256), block 256 (4 independent waves).
// ---------------------------------------------------------------------------
__global__ void __launch_bounds__(256)
attn_mfma(const bf16* __restrict__ qt, const bf16* __restrict__ kt,
          const bf16* __restrict__ vt, float* __restrict__ ao) {
    int wid   = blockIdx.x * 4 + (threadIdx.x >> 6);
    int lane  = threadIdx.x & 63;
    int bh    = wid >> 7;          // 8 (b,h) pairs
    int qtile = wid & 127;         // 128 tiles of 32 queries
    int i     = lane & 31;         // query col / key row / V d-row (role by use)
    int hl    = lane >> 5;

    const bf16* qb = qt + (size_t)bh * (N_TOK * 32) + (size_t)(qtile * 32) * 32;
    const bf16* kb = kt + (size_t)bh * (N_TOK * 32);
    const bf16* vb = vt + (size_t)bh * (32 * N_TOK);

    // Q as B-operand: B[k=d][col=i], lane holds d = 8*hl+e (+16 for q2)
    bf16x8 q1 = ld8(qb + i * 32 + hl * 8);
    bf16x8 q2 = ld8(qb + i * 32 + 16 + hl * 8);

    f32x16 O, Z;
#pragma unroll
    for (int r = 0; r < 16; ++r) { O[r] = 0.f; Z[r] = 0.f; }
    float l = 0.f;

    const bf16* kp0 = kb + (size_t)i * 32 + hl * 8;     // + j0*32 per chunk
    const bf16* vp0 = vb + (size_t)i * N_TOK + hl * 8;  // + j0 per chunk

    bf16x8 ka1 = ld8(kp0);
    bf16x8 ka2 = ld8(kp0 + 16);
    bf16x8 va1 = ld8(vp0);
    bf16x8 va2 = ld8(vp0 + 16);

    for (int j0 = 0; j0 < N_TOK; j0 += 32) {
        // software prefetch next chunk (wraps harmlessly on last iter)
        int jn = (j0 + 32) & (N_TOK - 1);
        bf16x8 nk1 = ld8(kp0 + (size_t)jn * 32);
        bf16x8 nk2 = ld8(kp0 + (size_t)jn * 32 + 16);
        bf16x8 nv1 = ld8(vp0 + jn);
        bf16x8 nv2 = ld8(vp0 + jn + 16);

        // S^T[j][i] = sum_d K[d][j] Q[d][i], d split into two K=16 mfmas
        f32x16 S = __builtin_amdgcn_mfma_f32_32x32x16_bf16(ka1, q1, Z, 0, 0, 0);
        S = __builtin_amdgcn_mfma_f32_32x32x16_bf16(ka2, q2, S, 0, 0, 0);

        // P = exp(S); lane (hl,i) holds rows j = (r&3)+8*(r>>2)+4*hl
        float p[16];
#pragma unroll
        for (int r = 0; r < 16; ++r) { p[r] = __expf(S[r]); l += p[r]; }

        unsigned pk0 = pack2(p[0], p[1]),   pk1 = pack2(p[2], p[3]);
        unsigned pk2 = pack2(p[4], p[5]),   pk3 = pack2(p[6], p[7]);
        unsigned pk4 = pack2(p[8], p[9]),   pk5 = pack2(p[10], p[11]);
        unsigned pk6 = pack2(p[12], p[13]), pk7 = pack2(p[14], p[15]);

        // build P^T B-operand: lane needs j = 8*hl+e; halves exchange via permlane32_swap
        i32x2 s1 = __builtin_amdgcn_permlane32_swap((int)pk0, (int)pk2, false, false);
        i32x2 s2 = __builtin_amdgcn_permlane32_swap((int)pk1, (int)pk3, false, false);
        i32x2 s3 = __builtin_amdgcn_permlane32_swap((int)pk4, (int)pk6, false, false);
        i32x2 s4 = __builtin_amdgcn_permlane32_swap((int)pk5, (int)pk7, false, false);

        uint4v B1 = {(unsigned)s1.x, (unsigned)s2.x, (unsigned)s1.y, (unsigned)s2.y};
        uint4v B2 = {(unsigned)s3.x, (unsigned)s4.x, (unsigned)s3.y, (unsigned)s4.y};

        // O[d][i] += V[d][j] P^T[j][i], two K=16 mfmas (j chunks of 16)
        O = __builtin_amdgcn_mfma_f32_32x32x16_bf16(va1, __builtin_bit_cast(bf16x8, B1), O, 0, 0, 0);
        O = __builtin_amdgcn_mfma_f32_32x32x16_bf16(va2, __builtin_bit_cast(bf16x8, B2), O, 0, 0, 0);

        ka1 = nk1; ka2 = nk2; va1 = nv1; va2 = nv2;
    }

    // l[i] = own half + partner half
    l += __shfl_xor(l, 32);
    float inv = 1.f / l;

    float* aop = ao + (size_t)bh * (32 * N_TOK) + qtile * 32 + i;
#pragma unroll
    for (int r = 0; r < 16; ++r) {
        int d = (r & 3) + 8 * (r >> 2) + 4 * hl;
        aop[(size_t)d * N_TOK] = O[r] * inv;
    }
}

// ---------------------------------------------------------------------------
// Kernel C: out[b][o][i] = sum_c w_out[o][c]*ao[b][c][i] + b_out[o] + x[b][o][i]
// grid (16, 4, 2), block 256; W via uniform loads.
// ---------------------------------------------------------------------------
__global__ void __launch_bounds__(256)
out_proj(const float* __restrict__ ao, const float* __restrict__ w,
         const float* __restrict__ bias, const float* __restrict__ x,
         float* __restrict__ out) {
    int i  = blockIdx.x * 256 + threadIdx.x;
    int o0 = blockIdx.y * 32;
    int b  = blockIdx.z;
    const float* ap = ao + (size_t)b * (128 * N_TOK) + i;
    const float* wp = w + (size_t)o0 * 128;
    float acc[32];
#pragma unroll
    for (int r = 0; r < 32; ++r) acc[r] = 0.f;
    for (int c = 0; c < 128; ++c) {
        float av = ap[(size_t)c * N_TOK];
#pragma unroll
        for (int r = 0; r < 32; ++r) acc[r] = fmaf(wp[r * 128 + c], av, acc[r]);
    }
#pragma unroll
    for (int r = 0; r < 32; ++r) {
        size_t idx = ((size_t)b * 128 + o0 + r) * N_TOK + i;
        out[idx] = acc[r] + bias[o0 + r] + x[idx];
    }
}

// ---------------------------------------------------------------------------
extern "C" void kernel_launch(void* const* d_in, const int* in_sizes, int n_in,
                              void* d_out, int out_size, void* d_ws, size_t ws_size,
                              hipStream_t stream) {
    const float* x     = (const float*)d_in[0];
    const float* w_qkv = (const float*)d_in[1];
    const float* w_out = (const float*)d_in[2];
    const float* b_out = (const float*)d_in[3];
    float* out = (float*)d_out;

    bf16* qt = (bf16*)d_ws;                        // [8][4096][32] bf16 = 2 MB
    bf16* kt = qt + (size_t)8 * N_TOK * 32;        // [8][4096][32] bf16 = 2 MB
    bf16* vt = kt + (size_t)8 * N_TOK * 32;        // [8][32][4096] bf16 = 2 MB
    float* ao = (float*)(vt + (size_t)8 * N_TOK * 32);  // [2][128][4096] f32 = 4 MB

    qkv_proj <<<dim3(16, 12, 2), 256, 0, stream>>>(x, w_qkv, qt, kt, vt);
    attn_mfma<<<dim3(256), 256, 0, stream>>>(qt, kt, vt, ao);
    out_proj <<<dim3(16, 4, 2), 256, 0, stream>>>(ao, w_out, b_out, x, out);
}

// Round 6
// 146.291 us; speedup vs baseline: 4.5884x; 1.4780x over previous
//
#include <hip/hip_runtime.h>
#include <hip/hip_bf16.h>

typedef __hip_bfloat16 bf16;
typedef float    f32x16 __attribute__((ext_vector_type(16)));
typedef __bf16   bf16x8 __attribute__((ext_vector_type(8)));
typedef unsigned uint4v __attribute__((ext_vector_type(4)));
typedef int      i32x2  __attribute__((ext_vector_type(2)));

#define N_TOK 4096
#define SCALE_L2E 0.2550348952703927f  // 32^-0.5 * log2(e), folded into q weights

__device__ __forceinline__ bf16x8 ld8(const bf16* p) { return *(const bf16x8*)p; }
__device__ __forceinline__ unsigned pack2(float a, float b) {
    unsigned short ua = __builtin_bit_cast(unsigned short, (__bf16)a);
    unsigned short ub = __builtin_bit_cast(unsigned short, (__bf16)b);
    return (unsigned)ua | ((unsigned)ub << 16);
}

// ---------------------------------------------------------------------------
// Kernel A: qkv projection. W staged in LDS [c][r] (float4-readable), f32 FMA,
// bf16 outputs in MFMA layouts: q_t/k_t[bh][tok][d] (q pre-scaled by
// SCALE*log2e), v[bh][d][tok].  grid (16, 24, 2), block 256.
// ---------------------------------------------------------------------------
__global__ void __launch_bounds__(256)
qkv_proj(const float* __restrict__ x, const float* __restrict__ w,
         bf16* __restrict__ qt, bf16* __restrict__ kt, bf16* __restrict__ vt) {
    int i  = blockIdx.x * 256 + threadIdx.x;
    int o0 = blockIdx.y * 16;
    int b  = blockIdx.z;
    bool isq = (o0 < 128);
    float sc = isq ? SCALE_L2E : 1.0f;
    __shared__ float wl[128][16];
    for (int t = threadIdx.x; t < 2048; t += 256) {
        int c = t & 127, r = t >> 7;
        wl[c][r] = w[(o0 + r) * 128 + c] * sc;
    }
    __syncthreads();
    const float* xp = x + (size_t)b * (128 * N_TOK) + i;
    float acc[16];
#pragma unroll
    for (int r = 0; r < 16; ++r) acc[r] = 0.f;
    for (int c = 0; c < 128; ++c) {
        float xv = xp[(size_t)c * N_TOK];
        const float4* w4 = (const float4*)wl[c];
#pragma unroll
        for (int t = 0; t < 4; ++t) {
            float4 wv4 = w4[t];
            acc[4 * t + 0] = fmaf(wv4.x, xv, acc[4 * t + 0]);
            acc[4 * t + 1] = fmaf(wv4.y, xv, acc[4 * t + 1]);
            acc[4 * t + 2] = fmaf(wv4.z, xv, acc[4 * t + 2]);
            acc[4 * t + 3] = fmaf(wv4.w, xv, acc[4 * t + 3]);
        }
    }
    if (o0 < 256) {  // q or k: [tok][d] bf16, 32 contiguous bytes per thread
        bf16* base = isq ? qt : kt;
        int   h    = (o0 & 127) >> 5;
        int   d0   = o0 & 31;  // 0 or 16
        unsigned wb[8];
#pragma unroll
        for (int k = 0; k < 8; ++k) wb[k] = pack2(acc[2 * k], acc[2 * k + 1]);
        uint4v* dst = (uint4v*)(base + ((size_t)(b * 4 + h) * N_TOK + i) * 32 + d0);
        dst[0] = (uint4v){wb[0], wb[1], wb[2], wb[3]};
        dst[1] = (uint4v){wb[4], wb[5], wb[6], wb[7]};
    } else {         // v: [d][tok] bf16, coalesced per-row stores
        int od = o0 - 256;
#pragma unroll
        for (int r = 0; r < 16; ++r)
            vt[((size_t)b * 128 + od + r) * N_TOK + i] = __float2bfloat16(acc[r]);
    }
}

// ---------------------------------------------------------------------------
// Kernel B: MFMA flash attention, swapped operands (S^T = K^T.Q), no-max
// softmax via exp2 (q pre-scaled by log2e), P->PV via pack + permlane32_swap.
// Key-split x4: each of 4 waves handles 1024 keys for the same 32 queries;
// exact partial combine in LDS (no-max => partials just add).
// grid 1024 (XCD-chunk swizzled), block 256.
// ---------------------------------------------------------------------------
__global__ void __launch_bounds__(256)
attn_mfma(const bf16* __restrict__ qt, const bf16* __restrict__ kt,
          const bf16* __restrict__ vt, float* __restrict__ ao) {
    int bid   = blockIdx.x;
    int swz   = (bid & 7) * 128 + (bid >> 3);  // bijective: XCD gets 128-block chunk
    int bh    = swz >> 7;
    int qtile = swz & 127;
    int lane  = threadIdx.x & 63;
    int wv    = threadIdx.x >> 6;
    int i     = lane & 31;
    int hl    = lane >> 5;

    const bf16* qb = qt + (size_t)bh * (N_TOK * 32) + (size_t)(qtile * 32) * 32;
    const bf16* kb = kt + (size_t)bh * (N_TOK * 32);
    const bf16* vb = vt + (size_t)bh * (32 * N_TOK);

    bf16x8 q1 = ld8(qb + i * 32 + hl * 8);
    bf16x8 q2 = ld8(qb + i * 32 + 16 + hl * 8);

    f32x16 O, Z;
#pragma unroll
    for (int r = 0; r < 16; ++r) { O[r] = 0.f; Z[r] = 0.f; }
    float l = 0.f;

    const bf16* kp0 = kb + ((size_t)(wv * 1024) + i) * 32 + hl * 8;
    const bf16* vp0 = vb + (size_t)i * N_TOK + wv * 1024 + hl * 8;

    bf16x8 ka1 = ld8(kp0);
    bf16x8 ka2 = ld8(kp0 + 16);
    bf16x8 va1 = ld8(vp0);
    bf16x8 va2 = ld8(vp0 + 16);

    for (int lj = 0; lj < 1024; lj += 32) {
        int jn = (lj + 32) & 1023;  // prefetch next chunk (wraps on last iter)
        bf16x8 nk1 = ld8(kp0 + (size_t)jn * 32);
        bf16x8 nk2 = ld8(kp0 + (size_t)jn * 32 + 16);
        bf16x8 nv1 = ld8(vp0 + jn);
        bf16x8 nv2 = ld8(vp0 + jn + 16);

        // S^T[j][i] = sum_d K[d][j] Q[d][i]  (already includes log2e factor)
        f32x16 S = __builtin_amdgcn_mfma_f32_32x32x16_bf16(ka1, q1, Z, 0, 0, 0);
        S = __builtin_amdgcn_mfma_f32_32x32x16_bf16(ka2, q2, S, 0, 0, 0);

        float p[16];
#pragma unroll
        for (int r = 0; r < 16; ++r) { p[r] = __builtin_amdgcn_exp2f(S[r]); l += p[r]; }

        unsigned pk0 = pack2(p[0], p[1]),   pk1 = pack2(p[2], p[3]);
        unsigned pk2 = pack2(p[4], p[5]),   pk3 = pack2(p[6], p[7]);
        unsigned pk4 = pack2(p[8], p[9]),   pk5 = pack2(p[10], p[11]);
        unsigned pk6 = pack2(p[12], p[13]), pk7 = pack2(p[14], p[15]);

        i32x2 s1 = __builtin_amdgcn_permlane32_swap((int)pk0, (int)pk2, false, false);
        i32x2 s2 = __builtin_amdgcn_permlane32_swap((int)pk1, (int)pk3, false, false);
        i32x2 s3 = __builtin_amdgcn_permlane32_swap((int)pk4, (int)pk6, false, false);
        i32x2 s4 = __builtin_amdgcn_permlane32_swap((int)pk5, (int)pk7, false, false);

        uint4v B1 = {(unsigned)s1.x, (unsigned)s2.x, (unsigned)s1.y, (unsigned)s2.y};
        uint4v B2 = {(unsigned)s3.x, (unsigned)s4.x, (unsigned)s3.y, (unsigned)s4.y};

        O = __builtin_amdgcn_mfma_f32_32x32x16_bf16(va1, __builtin_bit_cast(bf16x8, B1), O, 0, 0, 0);
        O = __builtin_amdgcn_mfma_f32_32x32x16_bf16(va2, __builtin_bit_cast(bf16x8, B2), O, 0, 0, 0);

        ka1 = nk1; ka2 = nk2; va1 = nv1; va2 = nv2;
    }

    l += __shfl_xor(l, 32);  // full per-wave denominator for query i

    // -------- exact combine of the 4 key-split partials ------------------
    __shared__ float osh[4][16][64];
    __shared__ float lsh[4][64];
#pragma unroll
    for (int r = 0; r < 16; ++r) osh[wv][r][lane] = O[r];
    lsh[wv][lane] = l;
    __syncthreads();
    float lt  = lsh[0][lane] + lsh[1][lane] + lsh[2][lane] + lsh[3][lane];
    float inv = 1.f / lt;
    float* aop = ao + (size_t)bh * (32 * N_TOK) + qtile * 32 + i;
#pragma unroll
    for (int r = 0; r < 4; ++r) {
        int rr = wv * 4 + r;
        float s = osh[0][rr][lane] + osh[1][rr][lane] + osh[2][rr][lane] + osh[3][rr][lane];
        int d = (rr & 3) + 8 * (rr >> 2) + 4 * hl;
        aop[(size_t)d * N_TOK] = s * inv;
    }
}

// ---------------------------------------------------------------------------
// Kernel C: out[b][o][i] = sum_c w_out[o][c]*ao[b][c][i] + b_out[o] + x[b][o][i]
// grid (16, 8, 2), block 256; W staged in LDS [c][r].
// ---------------------------------------------------------------------------
__global__ void __launch_bounds__(256)
out_proj(const float* __restrict__ ao, const float* __restrict__ w,
         const float* __restrict__ bias, const float* __restrict__ x,
         float* __restrict__ out) {
    int i  = blockIdx.x * 256 + threadIdx.x;
    int o0 = blockIdx.y * 16;
    int b  = blockIdx.z;
    __shared__ float wl[128][16];
    for (int t = threadIdx.x; t < 2048; t += 256) {
        int c = t & 127, r = t >> 7;
        wl[c][r] = w[(o0 + r) * 128 + c];
    }
    __syncthreads();
    const float* ap = ao + (size_t)b * (128 * N_TOK) + i;
    float acc[16];
#pragma unroll
    for (int r = 0; r < 16; ++r) acc[r] = 0.f;
    for (int c = 0; c < 128; ++c) {
        float av = ap[(size_t)c * N_TOK];
        const float4* w4 = (const float4*)wl[c];
#pragma unroll
        for (int t = 0; t < 4; ++t) {
            float4 wv4 = w4[t];
            acc[4 * t + 0] = fmaf(wv4.x, av, acc[4 * t + 0]);
            acc[4 * t + 1] = fmaf(wv4.y, av, acc[4 * t + 1]);
            acc[4 * t + 2] = fmaf(wv4.z, av, acc[4 * t + 2]);
            acc[4 * t + 3] = fmaf(wv4.w, av, acc[4 * t + 3]);
        }
    }
#pragma unroll
    for (int r = 0; r < 16; ++r) {
        size_t idx = ((size_t)b * 128 + o0 + r) * N_TOK + i;
        out[idx] = acc[r] + bias[o0 + r] + x[idx];
    }
}

// ---------------------------------------------------------------------------
extern "C" void kernel_launch(void* const* d_in, const int* in_sizes, int n_in,
                              void* d_out, int out_size, void* d_ws, size_t ws_size,
                              hipStream_t stream) {
    const float* x     = (const float*)d_in[0];
    const float* w_qkv = (const float*)d_in[1];
    const float* w_out = (const float*)d_in[2];
    const float* b_out = (const float*)d_in[3];
    float* out = (float*)d_out;

    bf16* qt = (bf16*)d_ws;                        // [8][4096][32] bf16 = 2 MB
    bf16* kt = qt + (size_t)8 * N_TOK * 32;        // [8][4096][32] bf16 = 2 MB
    bf16* vt = kt + (size_t)8 * N_TOK * 32;        // [8][32][4096] bf16 = 2 MB
    float* ao = (float*)(vt + (size_t)8 * N_TOK * 32);  // [2][128][4096] f32 = 4 MB

    qkv_proj <<<dim3(16, 24, 2), 256, 0, stream>>>(x, w_qkv, qt, kt, vt);
    attn_mfma<<<dim3(1024), 256, 0, stream>>>(qt, kt, vt, ao);
    out_proj <<<dim3(16, 8, 2), 256, 0, stream>>>(ao, w_out, b_out, x, out);
}

// Round 7
// 120.216 us; speedup vs baseline: 5.5836x; 1.2169x over previous
//
#include <hip/hip_runtime.h>
#include <hip/hip_bf16.h>

typedef __hip_bfloat16 bf16;
typedef float    f32x16 __attribute__((ext_vector_type(16)));
typedef __bf16   bf16x8 __attribute__((ext_vector_type(8)));
typedef unsigned uint4v __attribute__((ext_vector_type(4)));
typedef int      i32x2  __attribute__((ext_vector_type(2)));

#define N_TOK 4096
#define SCALE_L2E 0.2550348952703927f  // 32^-0.5 * log2(e), folded into q weights

__device__ __forceinline__ bf16x8 ld8(const bf16* p) { return *(const bf16x8*)p; }
__device__ __forceinline__ unsigned pack2(float a, float b) {
    unsigned short ua = __builtin_bit_cast(unsigned short, (__bf16)a);
    unsigned short ub = __builtin_bit_cast(unsigned short, (__bf16)b);
    return (unsigned)ua | ((unsigned)ub << 16);
}
__device__ __forceinline__ unsigned short f2b(float f) {
    return __builtin_bit_cast(unsigned short, (__bf16)f);
}
__device__ __forceinline__ __bf16 us2bf(unsigned short u) {
    return __builtin_bit_cast(__bf16, u);
}

// ---------------------------------------------------------------------------
// Kernel 0: convert weights to bf16 (q rows pre-scaled by SCALE*log2e).
// grid 256, block 256.
// ---------------------------------------------------------------------------
__global__ void wconv(const float* __restrict__ wqkv, const float* __restrict__ wout,
                      bf16* __restrict__ wq, bf16* __restrict__ wo) {
    int idx = blockIdx.x * 256 + threadIdx.x;
    if (idx < 384 * 128) {
        float sc = (idx < 128 * 128) ? SCALE_L2E : 1.0f;
        ((unsigned short*)wq)[idx] = f2b(wqkv[idx] * sc);
    } else {
        int j = idx - 384 * 128;
        ((unsigned short*)wo)[j] = f2b(wout[j]);
    }
}

// ---------------------------------------------------------------------------
// Kernel A: qkv projection via MFMA. Per block: one 32-token tile, batch b.
// LDS: X tile bf16 [c=128][tok=32]. Wave wv computes o-tiles {wv, 4+wv, 8+wv}:
//  q/k: swapped operands mfma(A=Xcol, B=Wrow) -> D[tok][d] (coalesced [tok][d])
//  v:   normal  operands mfma(A=Wrow, B=Xcol) -> D[d][tok] (coalesced [d][tok])
// grid (128, 2), block 256.
// ---------------------------------------------------------------------------
__global__ void __launch_bounds__(256)
qkv_mfma(const float* __restrict__ x, const bf16* __restrict__ wq,
         bf16* __restrict__ qt, bf16* __restrict__ kt, bf16* __restrict__ vt) {
    int tok0 = blockIdx.x * 32;
    int b    = blockIdx.y;
    __shared__ unsigned short xs[128][32];
    {   // stage: thread t -> row c = t>>1, 16-token half hf = t&1 (4 float4 loads)
        int c = threadIdx.x >> 1, hf = threadIdx.x & 1;
        const float4* x4 = (const float4*)(x + (size_t)b * (128 * N_TOK) +
                                           (size_t)c * N_TOK + tok0 + hf * 16);
        float4 a = x4[0], bb = x4[1], cc = x4[2], dd = x4[3];
        unsigned* dst = (unsigned*)&xs[c][hf * 16];
        dst[0] = pack2(a.x, a.y);  dst[1] = pack2(a.z, a.w);
        dst[2] = pack2(bb.x, bb.y); dst[3] = pack2(bb.z, bb.w);
        dst[4] = pack2(cc.x, cc.y); dst[5] = pack2(cc.z, cc.w);
        dst[6] = pack2(dd.x, dd.y); dst[7] = pack2(dd.z, dd.w);
    }
    __syncthreads();
    int lane = threadIdx.x & 63, wv = threadIdx.x >> 6;
    int i = lane & 31, hl = lane >> 5;

    // X column fragments (shared by all three tiles; A/B lane maps identical)
    bf16x8 xf[8];
#pragma unroll
    for (int kb = 0; kb < 8; ++kb) {
        bf16x8 f;
#pragma unroll
        for (int e = 0; e < 8; ++e) f[e] = us2bf(xs[kb * 16 + hl * 8 + e][i]);
        xf[kb] = f;
    }

    f32x16 Z;
#pragma unroll
    for (int r = 0; r < 16; ++r) Z[r] = 0.f;

    // ---- q tile (o = wv*32 .. +31): D[tok][d] ----
    {
        const bf16* wrow = wq + (size_t)(wv * 32 + i) * 128 + hl * 8;
        f32x16 D = Z;
#pragma unroll
        for (int kb = 0; kb < 8; ++kb)
            D = __builtin_amdgcn_mfma_f32_32x32x16_bf16(xf[kb], ld8(wrow + kb * 16), D, 0, 0, 0);
        unsigned short* dst = (unsigned short*)(qt + ((size_t)(b * 4 + wv) * N_TOK + tok0) * 32);
#pragma unroll
        for (int r = 0; r < 16; ++r) {
            int tr = (r & 3) + 8 * (r >> 2) + 4 * hl;
            dst[tr * 32 + i] = f2b(D[r]);
        }
    }
    // ---- k tile (o = 128 + wv*32): D[tok][d] ----
    {
        const bf16* wrow = wq + (size_t)(128 + wv * 32 + i) * 128 + hl * 8;
        f32x16 D = Z;
#pragma unroll
        for (int kb = 0; kb < 8; ++kb)
            D = __builtin_amdgcn_mfma_f32_32x32x16_bf16(xf[kb], ld8(wrow + kb * 16), D, 0, 0, 0);
        unsigned short* dst = (unsigned short*)(kt + ((size_t)(b * 4 + wv) * N_TOK + tok0) * 32);
#pragma unroll
        for (int r = 0; r < 16; ++r) {
            int tr = (r & 3) + 8 * (r >> 2) + 4 * hl;
            dst[tr * 32 + i] = f2b(D[r]);
        }
    }
    // ---- v tile (o = 256 + wv*32): D[d][tok] ----
    {
        const bf16* wrow = wq + (size_t)(256 + wv * 32 + i) * 128 + hl * 8;
        f32x16 D = Z;
#pragma unroll
        for (int kb = 0; kb < 8; ++kb)
            D = __builtin_amdgcn_mfma_f32_32x32x16_bf16(ld8(wrow + kb * 16), xf[kb], D, 0, 0, 0);
        unsigned short* dst = (unsigned short*)(vt + (size_t)(b * 4 + wv) * (32 * N_TOK) + tok0);
#pragma unroll
        for (int r = 0; r < 16; ++r) {
            int dr = (r & 3) + 8 * (r >> 2) + 4 * hl;
            dst[(size_t)dr * N_TOK + i] = f2b(D[r]);
        }
    }
}

// ---------------------------------------------------------------------------
// Kernel B: MFMA flash attention, swapped QK^T, no-max softmax via exp2,
// P->PV via pack + permlane32_swap. Key-split x8 (512 keys/wave), exact
// partial combine in LDS. ao output bf16 [b][c][tok].
// grid 1024 (XCD-chunk swizzled), block 512.
// ---------------------------------------------------------------------------
__global__ void __launch_bounds__(512)
attn_mfma(const bf16* __restrict__ qt, const bf16* __restrict__ kt,
          const bf16* __restrict__ vt, bf16* __restrict__ ao) {
    int bid   = blockIdx.x;
    int swz   = (bid & 7) * 128 + (bid >> 3);  // bijective: XCD gets 128-block chunk
    int bh    = swz >> 7;
    int qtile = swz & 127;
    int lane  = threadIdx.x & 63;
    int wv    = threadIdx.x >> 6;
    int i     = lane & 31;
    int hl    = lane >> 5;

    const bf16* qb = qt + (size_t)bh * (N_TOK * 32) + (size_t)(qtile * 32) * 32;
    const bf16* kb = kt + (size_t)bh * (N_TOK * 32);
    const bf16* vb = vt + (size_t)bh * (32 * N_TOK);

    bf16x8 q1 = ld8(qb + i * 32 + hl * 8);
    bf16x8 q2 = ld8(qb + i * 32 + 16 + hl * 8);

    f32x16 O, Z;
#pragma unroll
    for (int r = 0; r < 16; ++r) { O[r] = 0.f; Z[r] = 0.f; }
    float l = 0.f;

    const bf16* kp0 = kb + ((size_t)(wv * 512) + i) * 32 + hl * 8;
    const bf16* vp0 = vb + (size_t)i * N_TOK + wv * 512 + hl * 8;

    bf16x8 ka1 = ld8(kp0);
    bf16x8 ka2 = ld8(kp0 + 16);
    bf16x8 va1 = ld8(vp0);
    bf16x8 va2 = ld8(vp0 + 16);

    for (int lj = 0; lj < 512; lj += 32) {
        int jn = (lj + 32) & 511;  // prefetch next chunk (wraps on last iter)
        bf16x8 nk1 = ld8(kp0 + (size_t)jn * 32);
        bf16x8 nk2 = ld8(kp0 + (size_t)jn * 32 + 16);
        bf16x8 nv1 = ld8(vp0 + jn);
        bf16x8 nv2 = ld8(vp0 + jn + 16);

        f32x16 S = __builtin_amdgcn_mfma_f32_32x32x16_bf16(ka1, q1, Z, 0, 0, 0);
        S = __builtin_amdgcn_mfma_f32_32x32x16_bf16(ka2, q2, S, 0, 0, 0);

        float p[16];
#pragma unroll
        for (int r = 0; r < 16; ++r) { p[r] = __builtin_amdgcn_exp2f(S[r]); l += p[r]; }

        unsigned pk0 = pack2(p[0], p[1]),   pk1 = pack2(p[2], p[3]);
        unsigned pk2 = pack2(p[4], p[5]),   pk3 = pack2(p[6], p[7]);
        unsigned pk4 = pack2(p[8], p[9]),   pk5 = pack2(p[10], p[11]);
        unsigned pk6 = pack2(p[12], p[13]), pk7 = pack2(p[14], p[15]);

        i32x2 s1 = __builtin_amdgcn_permlane32_swap((int)pk0, (int)pk2, false, false);
        i32x2 s2 = __builtin_amdgcn_permlane32_swap((int)pk1, (int)pk3, false, false);
        i32x2 s3 = __builtin_amdgcn_permlane32_swap((int)pk4, (int)pk6, false, false);
        i32x2 s4 = __builtin_amdgcn_permlane32_swap((int)pk5, (int)pk7, false, false);

        uint4v B1 = {(unsigned)s1.x, (unsigned)s2.x, (unsigned)s1.y, (unsigned)s2.y};
        uint4v B2 = {(unsigned)s3.x, (unsigned)s4.x, (unsigned)s3.y, (unsigned)s4.y};

        O = __builtin_amdgcn_mfma_f32_32x32x16_bf16(va1, __builtin_bit_cast(bf16x8, B1), O, 0, 0, 0);
        O = __builtin_amdgcn_mfma_f32_32x32x16_bf16(va2, __builtin_bit_cast(bf16x8, B2), O, 0, 0, 0);

        ka1 = nk1; ka2 = nk2; va1 = nv1; va2 = nv2;
    }

    l += __shfl_xor(l, 32);  // per-wave denominator for query i

    // -------- exact combine of the 8 key-split partials ------------------
    __shared__ float osh[8][16][64];
    __shared__ float lsh[8][64];
#pragma unroll
    for (int r = 0; r < 16; ++r) osh[wv][r][lane] = O[r];
    lsh[wv][lane] = l;
    __syncthreads();
    float lt = 0.f;
#pragma unroll
    for (int s = 0; s < 8; ++s) lt += lsh[s][lane];
    float inv = 1.f / lt;
    unsigned short* aop = (unsigned short*)(ao + (size_t)bh * (32 * N_TOK) + qtile * 32);
#pragma unroll
    for (int r = 0; r < 2; ++r) {
        int rr = wv * 2 + r;
        float s = 0.f;
#pragma unroll
        for (int q = 0; q < 8; ++q) s += osh[q][rr][lane];
        int d = (rr & 3) + 8 * (rr >> 2) + 4 * hl;
        aop[(size_t)d * N_TOK + i] = f2b(s * inv);
    }
}

// ---------------------------------------------------------------------------
// Kernel C: out projection via MFMA + bias + residual.
// Per block: one 32-token tile; wave wv does o-tile wv (o0 = wv*32).
// grid (128, 2), block 256.
// ---------------------------------------------------------------------------
__global__ void __launch_bounds__(256)
out_mfma(const bf16* __restrict__ ao, const bf16* __restrict__ wo,
         const float* __restrict__ bias, const float* __restrict__ x,
         float* __restrict__ out) {
    int tok0 = blockIdx.x * 32;
    int b    = blockIdx.y;
    __shared__ unsigned short as_[128][32];
    {   // stage ao tile (already bf16): linear copy, 2x 16B per thread
        int c = threadIdx.x >> 1, hf = threadIdx.x & 1;
        const uint4v* src = (const uint4v*)(ao + (size_t)b * (128 * N_TOK) +
                                            (size_t)c * N_TOK + tok0 + hf * 16);
        uint4v v0 = src[0], v1 = src[1];
        uint4v* dst = (uint4v*)&as_[c][hf * 16];
        dst[0] = v0; dst[1] = v1;
    }
    __syncthreads();
    int lane = threadIdx.x & 63, wv = threadIdx.x >> 6;
    int i = lane & 31, hl = lane >> 5;

    bf16x8 af[8];
#pragma unroll
    for (int kb = 0; kb < 8; ++kb) {
        bf16x8 f;
#pragma unroll
        for (int e = 0; e < 8; ++e) f[e] = us2bf(as_[kb * 16 + hl * 8 + e][i]);
        af[kb] = f;
    }

    f32x16 D;
#pragma unroll
    for (int r = 0; r < 16; ++r) D[r] = 0.f;
    const bf16* wrow = wo + (size_t)(wv * 32 + i) * 128 + hl * 8;
#pragma unroll
    for (int kb = 0; kb < 8; ++kb)
        D = __builtin_amdgcn_mfma_f32_32x32x16_bf16(ld8(wrow + kb * 16), af[kb], D, 0, 0, 0);

#pragma unroll
    for (int r = 0; r < 16; ++r) {
        int o_r = wv * 32 + (r & 3) + 8 * (r >> 2) + 4 * hl;
        size_t idx = ((size_t)b * 128 + o_r) * N_TOK + tok0 + i;
        out[idx] = D[r] + bias[o_r] + x[idx];
    }
}

// ---------------------------------------------------------------------------
extern "C" void kernel_launch(void* const* d_in, const int* in_sizes, int n_in,
                              void* d_out, int out_size, void* d_ws, size_t ws_size,
                              hipStream_t stream) {
    const float* x     = (const float*)d_in[0];
    const float* w_qkv = (const float*)d_in[1];
    const float* w_out = (const float*)d_in[2];
    const float* b_out = (const float*)d_in[3];
    float* out = (float*)d_out;

    bf16* qt = (bf16*)d_ws;                          // [8][4096][32] bf16 = 2 MB
    bf16* kt = qt + (size_t)8 * N_TOK * 32;          // [8][4096][32] bf16 = 2 MB
    bf16* vt = kt + (size_t)8 * N_TOK * 32;          // [8][32][4096] bf16 = 2 MB
    bf16* ao = vt + (size_t)8 * N_TOK * 32;          // [2][128][4096] bf16 = 2 MB
    bf16* wq = ao + (size_t)2 * 128 * N_TOK;         // [384][128] bf16
    bf16* wo = wq + (size_t)384 * 128;               // [128][128] bf16

    wconv    <<<dim3(256), 256, 0, stream>>>(w_qkv, w_out, wq, wo);
    qkv_mfma <<<dim3(128, 2), 256, 0, stream>>>(x, wq, qt, kt, vt);
    attn_mfma<<<dim3(1024), 512, 0, stream>>>(qt, kt, vt, ao);
    out_mfma <<<dim3(128, 2), 256, 0, stream>>>(ao, wo, b_out, x, out);
}

// Round 8
// 118.574 us; speedup vs baseline: 5.6610x; 1.0139x over previous
//
#include <hip/hip_runtime.h>
#include <hip/hip_bf16.h>

typedef __hip_bfloat16 bf16;
typedef float    f32x16 __attribute__((ext_vector_type(16)));
typedef __bf16   bf16x8 __attribute__((ext_vector_type(8)));
typedef unsigned uint4v __attribute__((ext_vector_type(4)));
typedef int      i32x2  __attribute__((ext_vector_type(2)));

#define N_TOK 4096
#define SCALE_L2E 0.2550348952703927f  // 32^-0.5 * log2(e), folded into q weights

__device__ __forceinline__ bf16x8 ld8(const bf16* p) { return *(const bf16x8*)p; }
__device__ __forceinline__ unsigned pack2(float a, float b) {
    unsigned short ua = __builtin_bit_cast(unsigned short, (__bf16)a);
    unsigned short ub = __builtin_bit_cast(unsigned short, (__bf16)b);
    return (unsigned)ua | ((unsigned)ub << 16);
}
__device__ __forceinline__ unsigned short f2b(float f) {
    return __builtin_bit_cast(unsigned short, (__bf16)f);
}
__device__ __forceinline__ __bf16 us2bf(unsigned short u) {
    return __builtin_bit_cast(__bf16, u);
}
// W fragment from LDS row (pad 132 => 8B-aligned only; two b64 reads, 2-way banks = free)
__device__ __forceinline__ bf16x8 ldw(const unsigned short* rowp) {
    uint2 lo = *(const uint2*)rowp;
    uint2 hi = *(const uint2*)(rowp + 4);
    uint4v u = {lo.x, lo.y, hi.x, hi.y};
    return __builtin_bit_cast(bf16x8, u);
}

// ---------------------------------------------------------------------------
// Kernel A: qkv projection via MFMA, one q/k/v type per blockIdx.z.
// W (f32) converted to bf16 in LDS in-kernel (q rows pre-scaled SCALE*log2e).
//  q/k: swapped operands mfma(A=Xcol, B=Wrow) -> D[tok][d] -> qt/kt [bh][tok][d]
//  v:   normal  operands mfma(A=Wrow, B=Xcol) -> D[d][tok] -> vt [bh][d][tok]
// grid (128, 2, 3), block 256.
// ---------------------------------------------------------------------------
__global__ void __launch_bounds__(256)
qkv_mfma(const float* __restrict__ x, const float* __restrict__ w,
         bf16* __restrict__ qt, bf16* __restrict__ kt, bf16* __restrict__ vt) {
    int tok0 = blockIdx.x * 32;
    int b    = blockIdx.y;
    int z    = blockIdx.z;          // 0=q, 1=k, 2=v
    __shared__ unsigned short xs[128][32];
    __shared__ unsigned short wl[128][132];  // +4 pad: b64 reads 2-way-free
    {   // stage X tile: thread t -> row c = t>>1, 16-token half hf = t&1
        int c = threadIdx.x >> 1, hf = threadIdx.x & 1;
        const float4* x4 = (const float4*)(x + (size_t)b * (128 * N_TOK) +
                                           (size_t)c * N_TOK + tok0 + hf * 16);
        float4 a = x4[0], bb = x4[1], cc = x4[2], dd = x4[3];
        unsigned* dst = (unsigned*)&xs[c][hf * 16];
        dst[0] = pack2(a.x, a.y);   dst[1] = pack2(a.z, a.w);
        dst[2] = pack2(bb.x, bb.y); dst[3] = pack2(bb.z, bb.w);
        dst[4] = pack2(cc.x, cc.y); dst[5] = pack2(cc.z, cc.w);
        dst[6] = pack2(dd.x, dd.y); dst[7] = pack2(dd.z, dd.w);
    }
    {   // stage + convert this type's W[128][128] -> LDS bf16
        float sc = (z == 0) ? SCALE_L2E : 1.0f;
        const float4* wb4 = (const float4*)(w + (size_t)z * 128 * 128);
#pragma unroll
        for (int s = 0; s < 16; ++s) {
            int i4 = threadIdx.x + s * 256;
            int o  = i4 >> 5, c4 = (i4 & 31) * 4;
            float4 wv4 = wb4[i4];
            *(uint2*)&wl[o][c4] = make_uint2(pack2(wv4.x * sc, wv4.y * sc),
                                             pack2(wv4.z * sc, wv4.w * sc));
        }
    }
    __syncthreads();
    int lane = threadIdx.x & 63, wv = threadIdx.x >> 6;
    int i = lane & 31, hl = lane >> 5;

    bf16x8 xf[8], wf[8];
#pragma unroll
    for (int kb = 0; kb < 8; ++kb) {
        bf16x8 f;
#pragma unroll
        for (int e = 0; e < 8; ++e) f[e] = us2bf(xs[kb * 16 + hl * 8 + e][i]);
        xf[kb] = f;
        wf[kb] = ldw(&wl[wv * 32 + i][kb * 16 + hl * 8]);
    }

    f32x16 D;
#pragma unroll
    for (int r = 0; r < 16; ++r) D[r] = 0.f;

    if (z < 2) {  // q or k: D[tok][d]
#pragma unroll
        for (int kb = 0; kb < 8; ++kb)
            D = __builtin_amdgcn_mfma_f32_32x32x16_bf16(xf[kb], wf[kb], D, 0, 0, 0);
        bf16* base = (z == 0) ? qt : kt;
        unsigned short* dst = (unsigned short*)(base + ((size_t)(b * 4 + wv) * N_TOK + tok0) * 32);
#pragma unroll
        for (int r = 0; r < 16; ++r) {
            int tr = (r & 3) + 8 * (r >> 2) + 4 * hl;
            dst[tr * 32 + i] = f2b(D[r]);
        }
    } else {      // v: D[d][tok]
#pragma unroll
        for (int kb = 0; kb < 8; ++kb)
            D = __builtin_amdgcn_mfma_f32_32x32x16_bf16(wf[kb], xf[kb], D, 0, 0, 0);
        unsigned short* dst = (unsigned short*)(vt + (size_t)(b * 4 + wv) * (32 * N_TOK) + tok0);
#pragma unroll
        for (int r = 0; r < 16; ++r) {
            int dr = (r & 3) + 8 * (r >> 2) + 4 * hl;
            dst[(size_t)dr * N_TOK + i] = f2b(D[r]);
        }
    }
}

// ---------------------------------------------------------------------------
// Kernel B: MFMA flash attention, swapped QK^T, no-max softmax via exp2,
// P->PV via pack + permlane32_swap. l computed on the MFMA pipe via
// Ol = mfma(ones, P, Ol) (replaces 16-deep serial VALU chain + final shfl).
// Key-split x8 (512 keys/wave), depth-3 prefetch ring, LDS partial combine.
// grid 1024 (XCD-chunk swizzled), block 512.
// ---------------------------------------------------------------------------
__global__ void __launch_bounds__(512)
attn_mfma(const bf16* __restrict__ qt, const bf16* __restrict__ kt,
          const bf16* __restrict__ vt, bf16* __restrict__ ao) {
    int bid   = blockIdx.x;
    int swz   = (bid & 7) * 128 + (bid >> 3);  // bijective XCD chunking
    int bh    = swz >> 7;
    int qtile = swz & 127;
    int lane  = threadIdx.x & 63;
    int wv    = threadIdx.x >> 6;
    int i     = lane & 31;
    int hl    = lane >> 5;

    const bf16* qb = qt + (size_t)bh * (N_TOK * 32) + (size_t)(qtile * 32) * 32;
    const bf16* kp0 = kt + (size_t)bh * (N_TOK * 32) + ((size_t)(wv * 512) + i) * 32 + hl * 8;
    const bf16* vp0 = vt + (size_t)bh * (32 * N_TOK) + (size_t)i * N_TOK + wv * 512 + hl * 8;

    bf16x8 q1 = ld8(qb + i * 32 + hl * 8);
    bf16x8 q2 = ld8(qb + i * 32 + 16 + hl * 8);

    bf16x8 ones;
#pragma unroll
    for (int e = 0; e < 8; ++e) ones[e] = us2bf(0x3F80);  // 1.0bf

    f32x16 O, Ol, Z;
#pragma unroll
    for (int r = 0; r < 16; ++r) { O[r] = 0.f; Ol[r] = 0.f; Z[r] = 0.f; }

    // depth-3 prefetch ring (fully unrolled => compile-time indices)
    bf16x8 kr1[3], kr2[3], vr1[3], vr2[3];
#pragma unroll
    for (int t = 0; t < 3; ++t) {
        kr1[t] = ld8(kp0 + (size_t)(t * 32) * 32);
        kr2[t] = ld8(kp0 + (size_t)(t * 32) * 32 + 16);
        vr1[t] = ld8(vp0 + t * 32);
        vr2[t] = ld8(vp0 + t * 32 + 16);
    }

#pragma unroll
    for (int it = 0; it < 16; ++it) {
        const int cur = it % 3;
        const int jn  = (it * 32 + 96) & 511;  // refill 3 chunks ahead (wraps at tail)

        f32x16 S = __builtin_amdgcn_mfma_f32_32x32x16_bf16(kr1[cur], q1, Z, 0, 0, 0);
        S = __builtin_amdgcn_mfma_f32_32x32x16_bf16(kr2[cur], q2, S, 0, 0, 0);

        // refill K slot (after last use)
        kr1[cur] = ld8(kp0 + (size_t)jn * 32);
        kr2[cur] = ld8(kp0 + (size_t)jn * 32 + 16);

        float p[16];
#pragma unroll
        for (int r = 0; r < 16; ++r) p[r] = __builtin_amdgcn_exp2f(S[r]);

        unsigned pk0 = pack2(p[0], p[1]),   pk1 = pack2(p[2], p[3]);
        unsigned pk2 = pack2(p[4], p[5]),   pk3 = pack2(p[6], p[7]);
        unsigned pk4 = pack2(p[8], p[9]),   pk5 = pack2(p[10], p[11]);
        unsigned pk6 = pack2(p[12], p[13]), pk7 = pack2(p[14], p[15]);

        i32x2 s1 = __builtin_amdgcn_permlane32_swap((int)pk0, (int)pk2, false, false);
        i32x2 s2 = __builtin_amdgcn_permlane32_swap((int)pk1, (int)pk3, false, false);
        i32x2 s3 = __builtin_amdgcn_permlane32_swap((int)pk4, (int)pk6, false, false);
        i32x2 s4 = __builtin_amdgcn_permlane32_swap((int)pk5, (int)pk7, false, false);

        uint4v B1u = {(unsigned)s1.x, (unsigned)s2.x, (unsigned)s1.y, (unsigned)s2.y};
        uint4v B2u = {(unsigned)s3.x, (unsigned)s4.x, (unsigned)s3.y, (unsigned)s4.y};
        bf16x8 B1 = __builtin_bit_cast(bf16x8, B1u);
        bf16x8 B2 = __builtin_bit_cast(bf16x8, B2u);

        O  = __builtin_amdgcn_mfma_f32_32x32x16_bf16(vr1[cur], B1, O, 0, 0, 0);
        O  = __builtin_amdgcn_mfma_f32_32x32x16_bf16(vr2[cur], B2, O, 0, 0, 0);
        Ol = __builtin_amdgcn_mfma_f32_32x32x16_bf16(ones, B1, Ol, 0, 0, 0);
        Ol = __builtin_amdgcn_mfma_f32_32x32x16_bf16(ones, B2, Ol, 0, 0, 0);

        // refill V slot
        vr1[cur] = ld8(vp0 + jn);
        vr2[cur] = ld8(vp0 + jn + 16);
    }

    // -------- exact combine of the 8 key-split partials ------------------
    __shared__ float osh[8][16][64];
    __shared__ float lsh[8][64];
#pragma unroll
    for (int r = 0; r < 16; ++r) osh[wv][r][lane] = O[r];
    lsh[wv][lane] = Ol[0];  // all 16 rows of Ol identical = sum_j P[j][i]
    __syncthreads();
    float lt = 0.f;
#pragma unroll
    for (int s = 0; s < 8; ++s) lt += lsh[s][lane];
    float inv = 1.f / lt;
    unsigned short* aop = (unsigned short*)(ao + (size_t)bh * (32 * N_TOK) + qtile * 32);
#pragma unroll
    for (int r = 0; r < 2; ++r) {
        int rr = wv * 2 + r;
        float s = 0.f;
#pragma unroll
        for (int q = 0; q < 8; ++q) s += osh[q][rr][lane];
        int d = (rr & 3) + 8 * (rr >> 2) + 4 * hl;
        aop[(size_t)d * N_TOK + i] = f2b(s * inv);
    }
}

// ---------------------------------------------------------------------------
// Kernel C: out projection via MFMA + bias + residual; W converted in-LDS.
// grid (128, 2), block 256.
// ---------------------------------------------------------------------------
__global__ void __launch_bounds__(256)
out_mfma(const bf16* __restrict__ ao, const float* __restrict__ w,
         const float* __restrict__ bias, const float* __restrict__ x,
         float* __restrict__ out) {
    int tok0 = blockIdx.x * 32;
    int b    = blockIdx.y;
    __shared__ unsigned short as_[128][32];
    __shared__ unsigned short wl[128][132];
    {   // stage ao tile (already bf16): linear 2x16B per thread
        int c = threadIdx.x >> 1, hf = threadIdx.x & 1;
        const uint4v* src = (const uint4v*)(ao + (size_t)b * (128 * N_TOK) +
                                            (size_t)c * N_TOK + tok0 + hf * 16);
        uint4v v0 = src[0], v1 = src[1];
        uint4v* dst = (uint4v*)&as_[c][hf * 16];
        dst[0] = v0; dst[1] = v1;
    }
    {   // stage + convert W_out[128][128] -> LDS bf16
        const float4* wb4 = (const float4*)w;
#pragma unroll
        for (int s = 0; s < 16; ++s) {
            int i4 = threadIdx.x + s * 256;
            int o  = i4 >> 5, c4 = (i4 & 31) * 4;
            float4 wv4 = wb4[i4];
            *(uint2*)&wl[o][c4] = make_uint2(pack2(wv4.x, wv4.y), pack2(wv4.z, wv4.w));
        }
    }
    __syncthreads();
    int lane = threadIdx.x & 63, wv = threadIdx.x >> 6;
    int i = lane & 31, hl = lane >> 5;

    bf16x8 af[8], wf[8];
#pragma unroll
    for (int kb = 0; kb < 8; ++kb) {
        bf16x8 f;
#pragma unroll
        for (int e = 0; e < 8; ++e) f[e] = us2bf(as_[kb * 16 + hl * 8 + e][i]);
        af[kb] = f;
        wf[kb] = ldw(&wl[wv * 32 + i][kb * 16 + hl * 8]);
    }

    f32x16 D;
#pragma unroll
    for (int r = 0; r < 16; ++r) D[r] = 0.f;
#pragma unroll
    for (int kb = 0; kb < 8; ++kb)
        D = __builtin_amdgcn_mfma_f32_32x32x16_bf16(wf[kb], af[kb], D, 0, 0, 0);

#pragma unroll
    for (int r = 0; r < 16; ++r) {
        int o_r = wv * 32 + (r & 3) + 8 * (r >> 2) + 4 * hl;
        size_t idx = ((size_t)b * 128 + o_r) * N_TOK + tok0 + i;
        out[idx] = D[r] + bias[o_r] + x[idx];
    }
}

// ---------------------------------------------------------------------------
extern "C" void kernel_launch(void* const* d_in, const int* in_sizes, int n_in,
                              void* d_out, int out_size, void* d_ws, size_t ws_size,
                              hipStream_t stream) {
    const float* x     = (const float*)d_in[0];
    const float* w_qkv = (const float*)d_in[1];
    const float* w_out = (const float*)d_in[2];
    const float* b_out = (const float*)d_in[3];
    float* out = (float*)d_out;

    bf16* qt = (bf16*)d_ws;                          // [8][4096][32] bf16 = 2 MB
    bf16* kt = qt + (size_t)8 * N_TOK * 32;          // [8][4096][32] bf16 = 2 MB
    bf16* vt = kt + (size_t)8 * N_TOK * 32;          // [8][32][4096] bf16 = 2 MB
    bf16* ao = vt + (size_t)8 * N_TOK * 32;          // [2][128][4096] bf16 = 2 MB

    qkv_mfma <<<dim3(128, 2, 3), 256, 0, stream>>>(x, w_qkv, qt, kt, vt);
    attn_mfma<<<dim3(1024), 512, 0, stream>>>(qt, kt, vt, ao);
    out_mfma <<<dim3(128, 2), 256, 0, stream>>>(ao, w_out, b_out, x, out);
}

// Round 9
// 112.446 us; speedup vs baseline: 5.9695x; 1.0545x over previous
//
#include <hip/hip_runtime.h>
#include <hip/hip_bf16.h>

typedef __hip_bfloat16 bf16;
typedef float    f32x16 __attribute__((ext_vector_type(16)));
typedef __bf16   bf16x8 __attribute__((ext_vector_type(8)));
typedef unsigned uint4v __attribute__((ext_vector_type(4)));
typedef int      i32x2  __attribute__((ext_vector_type(2)));

#define N_TOK 4096
#define SCALE_L2E 0.2550348952703927f  // 32^-0.5 * log2(e), folded into q weights

__device__ __forceinline__ bf16x8 ld8(const bf16* p) { return *(const bf16x8*)p; }
__device__ __forceinline__ unsigned pack2(float a, float b) {
    unsigned short ua = __builtin_bit_cast(unsigned short, (__bf16)a);
    unsigned short ub = __builtin_bit_cast(unsigned short, (__bf16)b);
    return (unsigned)ua | ((unsigned)ub << 16);
}
__device__ __forceinline__ unsigned short f2b(float f) {
    return __builtin_bit_cast(unsigned short, (__bf16)f);
}
__device__ __forceinline__ __bf16 us2bf(unsigned short u) {
    return __builtin_bit_cast(__bf16, u);
}
__device__ __forceinline__ bf16x8 ldw(const unsigned short* rowp) {
    uint2 lo = *(const uint2*)rowp;
    uint2 hi = *(const uint2*)(rowp + 4);
    uint4v u = {lo.x, lo.y, hi.x, hi.y};
    return __builtin_bit_cast(bf16x8, u);
}

// ---------------------------------------------------------------------------
// Kernel A: qkv projection via MFMA (unchanged from round 8).
// grid (128, 2, 3), block 256.
// ---------------------------------------------------------------------------
__global__ void __launch_bounds__(256)
qkv_mfma(const float* __restrict__ x, const float* __restrict__ w,
         bf16* __restrict__ qt, bf16* __restrict__ kt, bf16* __restrict__ vt) {
    int tok0 = blockIdx.x * 32;
    int b    = blockIdx.y;
    int z    = blockIdx.z;          // 0=q, 1=k, 2=v
    __shared__ unsigned short xs[128][32];
    __shared__ unsigned short wl[128][132];
    {
        int c = threadIdx.x >> 1, hf = threadIdx.x & 1;
        const float4* x4 = (const float4*)(x + (size_t)b * (128 * N_TOK) +
                                           (size_t)c * N_TOK + tok0 + hf * 16);
        float4 a = x4[0], bb = x4[1], cc = x4[2], dd = x4[3];
        unsigned* dst = (unsigned*)&xs[c][hf * 16];
        dst[0] = pack2(a.x, a.y);   dst[1] = pack2(a.z, a.w);
        dst[2] = pack2(bb.x, bb.y); dst[3] = pack2(bb.z, bb.w);
        dst[4] = pack2(cc.x, cc.y); dst[5] = pack2(cc.z, cc.w);
        dst[6] = pack2(dd.x, dd.y); dst[7] = pack2(dd.z, dd.w);
    }
    {
        float sc = (z == 0) ? SCALE_L2E : 1.0f;
        const float4* wb4 = (const float4*)(w + (size_t)z * 128 * 128);
#pragma unroll
        for (int s = 0; s < 16; ++s) {
            int i4 = threadIdx.x + s * 256;
            int o  = i4 >> 5, c4 = (i4 & 31) * 4;
            float4 wv4 = wb4[i4];
            *(uint2*)&wl[o][c4] = make_uint2(pack2(wv4.x * sc, wv4.y * sc),
                                             pack2(wv4.z * sc, wv4.w * sc));
        }
    }
    __syncthreads();
    int lane = threadIdx.x & 63, wv = threadIdx.x >> 6;
    int i = lane & 31, hl = lane >> 5;

    bf16x8 xf[8], wf[8];
#pragma unroll
    for (int kb = 0; kb < 8; ++kb) {
        bf16x8 f;
#pragma unroll
        for (int e = 0; e < 8; ++e) f[e] = us2bf(xs[kb * 16 + hl * 8 + e][i]);
        xf[kb] = f;
        wf[kb] = ldw(&wl[wv * 32 + i][kb * 16 + hl * 8]);
    }

    f32x16 D;
#pragma unroll
    for (int r = 0; r < 16; ++r) D[r] = 0.f;

    if (z < 2) {
#pragma unroll
        for (int kb = 0; kb < 8; ++kb)
            D = __builtin_amdgcn_mfma_f32_32x32x16_bf16(xf[kb], wf[kb], D, 0, 0, 0);
        bf16* base = (z == 0) ? qt : kt;
        unsigned short* dst = (unsigned short*)(base + ((size_t)(b * 4 + wv) * N_TOK + tok0) * 32);
#pragma unroll
        for (int r = 0; r < 16; ++r) {
            int tr = (r & 3) + 8 * (r >> 2) + 4 * hl;
            dst[tr * 32 + i] = f2b(D[r]);
        }
    } else {
#pragma unroll
        for (int kb = 0; kb < 8; ++kb)
            D = __builtin_amdgcn_mfma_f32_32x32x16_bf16(wf[kb], xf[kb], D, 0, 0, 0);
        unsigned short* dst = (unsigned short*)(vt + (size_t)(b * 4 + wv) * (32 * N_TOK) + tok0);
#pragma unroll
        for (int r = 0; r < 16; ++r) {
            int dr = (r & 3) + 8 * (r >> 2) + 4 * hl;
            dst[(size_t)dr * N_TOK + i] = f2b(D[r]);
        }
    }
}

// ---------------------------------------------------------------------------
// Kernel B: MFMA flash attention with block-shared, double-buffered LDS K/V.
// Block = 512 thr = 8 waves = 4 qtiles x 2 key-halves, one bh, all 4096 keys
// in 64-key chunks. LDS is fragment-ordered: every ds_read_b128 is
// lane-linear (2-way bank alias = free); V units rotation-swizzled so the
// stage ds_writes are conflict-free too. Stage loads issued before compute,
// ds_write after (T14); one barrier per chunk (2-phase template).
// grid 256 = 8 bh x 32 qgroups (XCD-swizzled: XCD x owns bh x), block 512.
// ---------------------------------------------------------------------------
__global__ void __launch_bounds__(512)
attn_mfma(const bf16* __restrict__ qt, const bf16* __restrict__ kt,
          const bf16* __restrict__ vt, bf16* __restrict__ ao) {
    int bid = blockIdx.x;
    int swz = (bid & 7) * 32 + (bid >> 3);   // XCD x -> contiguous 32 blocks = bh x
    int bh  = swz >> 5;
    int g   = swz & 31;                       // qgroup: 128 queries
    int tid  = threadIdx.x;
    int lane = tid & 63, wv = tid >> 6;
    int qtl  = wv >> 1;                       // qtile owner 0..3
    int kh   = wv & 1;                        // key half of each chunk
    int i    = lane & 31, hl = lane >> 5;

    __shared__ uint4v lds[2][512];            // [buf][0:256 K | 256:512 V] 16B units
    __shared__ float  lsh[4][64];

    const bf16* qb = qt + (size_t)bh * (N_TOK * 32) + (size_t)(g * 128 + qtl * 32) * 32;
    const bf16* kb = kt + (size_t)bh * (N_TOK * 32);
    const bf16* vb = vt + (size_t)bh * (32 * N_TOK);

    bf16x8 q1 = ld8(qb + i * 32 + hl * 8);
    bf16x8 q2 = ld8(qb + i * 32 + 16 + hl * 8);

    // ---- staging role of this thread (one 16B unit per chunk) ----
    bool isK = tid < 256;
    int  u   = isK ? tid : tid - 256;
    // K unit u = (s*2+T)*64 + hl*32 + key  <-> global elem (j0+s*32+key)*32 + T*16 + hl*8
    int kgoff = (((u >> 7) * 32) + (u & 31)) * 32 + ((u >> 6) & 1) * 16 + ((u >> 5) & 1) * 8;
    // V unit u = i_*8 + c (global-coalesced)  -> LDS 256 + c*32 + ((i_+c)&31)
    int vgoff = (u >> 3) * N_TOK + (u & 7) * 8;
    int ldst  = isK ? u : (256 + (u & 7) * 32 + (((u >> 3) + (u & 7)) & 31));

    f32x16 O, Z;
#pragma unroll
    for (int r = 0; r < 16; ++r) { O[r] = 0.f; Z[r] = 0.f; }
    float l = 0.f;

    // fragment read indices (lane-linear)
    int kidx1 = kh * 128 + lane;        // ka1: T=0
    int kidx2 = kh * 128 + 64 + lane;   // ka2: T=1
    int cc0 = kh * 4 + hl,     vidx1 = 256 + cc0 * 32 + ((i + cc0) & 31);
    int cc1 = kh * 4 + 2 + hl, vidx2 = 256 + cc1 * 32 + ((i + cc1) & 31);

    // prologue: stage chunk 0
    lds[0][ldst] = isK ? *(const uint4v*)(kb + kgoff) : *(const uint4v*)(vb + vgoff);
    __syncthreads();

    for (int c = 0; c < 64; ++c) {
        int bf = c & 1;
        uint4v nx;
        if (c < 63) {   // issue next chunk's load early (hide L2 under compute)
            int j0 = (c + 1) * 64;
            nx = isK ? *(const uint4v*)(kb + (size_t)j0 * 32 + kgoff)
                     : *(const uint4v*)(vb + j0 + vgoff);
        }
        const uint4v* L = lds[bf];

        bf16x8 ka1 = __builtin_bit_cast(bf16x8, L[kidx1]);
        bf16x8 ka2 = __builtin_bit_cast(bf16x8, L[kidx2]);
        f32x16 S = __builtin_amdgcn_mfma_f32_32x32x16_bf16(ka1, q1, Z, 0, 0, 0);
        S = __builtin_amdgcn_mfma_f32_32x32x16_bf16(ka2, q2, S, 0, 0, 0);

        float p[16];
#pragma unroll
        for (int r = 0; r < 16; ++r) p[r] = __builtin_amdgcn_exp2f(S[r]);
        float s0 = (p[0] + p[1]) + (p[2] + p[3]);
        float s1 = (p[4] + p[5]) + (p[6] + p[7]);
        float s2 = (p[8] + p[9]) + (p[10] + p[11]);
        float s3 = (p[12] + p[13]) + (p[14] + p[15]);
        l += (s0 + s1) + (s2 + s3);

        unsigned pk0 = pack2(p[0], p[1]),   pk1 = pack2(p[2], p[3]);
        unsigned pk2 = pack2(p[4], p[5]),   pk3 = pack2(p[6], p[7]);
        unsigned pk4 = pack2(p[8], p[9]),   pk5 = pack2(p[10], p[11]);
        unsigned pk6 = pack2(p[12], p[13]), pk7 = pack2(p[14], p[15]);

        i32x2 t1 = __builtin_amdgcn_permlane32_swap((int)pk0, (int)pk2, false, false);
        i32x2 t2 = __builtin_amdgcn_permlane32_swap((int)pk1, (int)pk3, false, false);
        i32x2 t3 = __builtin_amdgcn_permlane32_swap((int)pk4, (int)pk6, false, false);
        i32x2 t4 = __builtin_amdgcn_permlane32_swap((int)pk5, (int)pk7, false, false);

        uint4v B1u = {(unsigned)t1.x, (unsigned)t2.x, (unsigned)t1.y, (unsigned)t2.y};
        uint4v B2u = {(unsigned)t3.x, (unsigned)t4.x, (unsigned)t3.y, (unsigned)t4.y};

        bf16x8 va1 = __builtin_bit_cast(bf16x8, L[vidx1]);
        bf16x8 va2 = __builtin_bit_cast(bf16x8, L[vidx2]);
        O = __builtin_amdgcn_mfma_f32_32x32x16_bf16(va1, __builtin_bit_cast(bf16x8, B1u), O, 0, 0, 0);
        O = __builtin_amdgcn_mfma_f32_32x32x16_bf16(va2, __builtin_bit_cast(bf16x8, B2u), O, 0, 0, 0);

        if (c < 63) lds[bf ^ 1][ldst] = nx;   // write after compute; barrier publishes
        __syncthreads();
    }

    // ---- combine the 2 key-half partials per qtile ----
    l += __shfl_xor(l, 32);                   // full l for this wave's keys
    float* fb = (float*)lds;                  // 16 KB scratch, loop barrier done
    if (kh == 1) {
#pragma unroll
        for (int r = 0; r < 16; ++r) fb[qtl * 1024 + r * 64 + lane] = O[r];
        lsh[qtl][lane] = l;
    }
    __syncthreads();
    if (kh == 0) {
        float lt  = l + lsh[qtl][lane];
        float inv = 1.f / lt;
        unsigned short* aop = (unsigned short*)(ao + (size_t)bh * (32 * N_TOK) + g * 128 + qtl * 32);
#pragma unroll
        for (int r = 0; r < 16; ++r) {
            float s = O[r] + fb[qtl * 1024 + r * 64 + lane];
            int d = (r & 3) + 8 * (r >> 2) + 4 * hl;
            aop[(size_t)d * N_TOK + i] = f2b(s * inv);
        }
    }
}

// ---------------------------------------------------------------------------
// Kernel C: out projection via MFMA + bias + residual (unchanged from round 8).
// grid (128, 2), block 256.
// ---------------------------------------------------------------------------
__global__ void __launch_bounds__(256)
out_mfma(const bf16* __restrict__ ao, const float* __restrict__ w,
         const float* __restrict__ bias, const float* __restrict__ x,
         float* __restrict__ out) {
    int tok0 = blockIdx.x * 32;
    int b    = blockIdx.y;
    __shared__ unsigned short as_[128][32];
    __shared__ unsigned short wl[128][132];
    {
        int c = threadIdx.x >> 1, hf = threadIdx.x & 1;
        const uint4v* src = (const uint4v*)(ao + (size_t)b * (128 * N_TOK) +
                                            (size_t)c * N_TOK + tok0 + hf * 16);
        uint4v v0 = src[0], v1 = src[1];
        uint4v* dst = (uint4v*)&as_[c][hf * 16];
        dst[0] = v0; dst[1] = v1;
    }
    {
        const float4* wb4 = (const float4*)w;
#pragma unroll
        for (int s = 0; s < 16; ++s) {
            int i4 = threadIdx.x + s * 256;
            int o  = i4 >> 5, c4 = (i4 & 31) * 4;
            float4 wv4 = wb4[i4];
            *(uint2*)&wl[o][c4] = make_uint2(pack2(wv4.x, wv4.y), pack2(wv4.z, wv4.w));
        }
    }
    __syncthreads();
    int lane = threadIdx.x & 63, wv = threadIdx.x >> 6;
    int i = lane & 31, hl = lane >> 5;

    bf16x8 af[8], wf[8];
#pragma unroll
    for (int kb = 0; kb < 8; ++kb) {
        bf16x8 f;
#pragma unroll
        for (int e = 0; e < 8; ++e) f[e] = us2bf(as_[kb * 16 + hl * 8 + e][i]);
        af[kb] = f;
        wf[kb] = ldw(&wl[wv * 32 + i][kb * 16 + hl * 8]);
    }

    f32x16 D;
#pragma unroll
    for (int r = 0; r < 16; ++r) D[r] = 0.f;
#pragma unroll
    for (int kb = 0; kb < 8; ++kb)
        D = __builtin_amdgcn_mfma_f32_32x32x16_bf16(wf[kb], af[kb], D, 0, 0, 0);

#pragma unroll
    for (int r = 0; r < 16; ++r) {
        int o_r = wv * 32 + (r & 3) + 8 * (r >> 2) + 4 * hl;
        size_t idx = ((size_t)b * 128 + o_r) * N_TOK + tok0 + i;
        out[idx] = D[r] + bias[o_r] + x[idx];
    }
}

// ---------------------------------------------------------------------------
extern "C" void kernel_launch(void* const* d_in, const int* in_sizes, int n_in,
                              void* d_out, int out_size, void* d_ws, size_t ws_size,
                              hipStream_t stream) {
    const float* x     = (const float*)d_in[0];
    const float* w_qkv = (const float*)d_in[1];
    const float* w_out = (const float*)d_in[2];
    const float* b_out = (const float*)d_in[3];
    float* out = (float*)d_out;

    bf16* qt = (bf16*)d_ws;                          // [8][4096][32] bf16 = 2 MB
    bf16* kt = qt + (size_t)8 * N_TOK * 32;          // [8][4096][32] bf16 = 2 MB
    bf16* vt = kt + (size_t)8 * N_TOK * 32;          // [8][32][4096] bf16 = 2 MB
    bf16* ao = vt + (size_t)8 * N_TOK * 32;          // [2][128][4096] bf16 = 2 MB

    qkv_mfma <<<dim3(128, 2, 3), 256, 0, stream>>>(x, w_qkv, qt, kt, vt);
    attn_mfma<<<dim3(256), 512, 0, stream>>>(qt, kt, vt, ao);
    out_mfma <<<dim3(128, 2), 256, 0, stream>>>(ao, w_out, b_out, x, out);
}

// Round 10
// 106.786 us; speedup vs baseline: 6.2859x; 1.0530x over previous
//
#include <hip/hip_runtime.h>
#include <hip/hip_bf16.h>

typedef __hip_bfloat16 bf16;
typedef float    f32x16 __attribute__((ext_vector_type(16)));
typedef __bf16   bf16x8 __attribute__((ext_vector_type(8)));
typedef unsigned uint4v __attribute__((ext_vector_type(4)));
typedef int      i32x2  __attribute__((ext_vector_type(2)));

#define N_TOK 4096
#define SCALE_L2E 0.2550348952703927f  // 32^-0.5 * log2(e), folded into q weights

__device__ __forceinline__ bf16x8 ld8(const bf16* p) { return *(const bf16x8*)p; }
__device__ __forceinline__ unsigned pack2(float a, float b) {
    unsigned short ua = __builtin_bit_cast(unsigned short, (__bf16)a);
    unsigned short ub = __builtin_bit_cast(unsigned short, (__bf16)b);
    return (unsigned)ua | ((unsigned)ub << 16);
}
__device__ __forceinline__ unsigned short f2b(float f) {
    return __builtin_bit_cast(unsigned short, (__bf16)f);
}
__device__ __forceinline__ __bf16 us2bf(unsigned short u) {
    return __builtin_bit_cast(__bf16, u);
}
__device__ __forceinline__ bf16x8 ldw(const unsigned short* rowp) {
    uint2 lo = *(const uint2*)rowp;
    uint2 hi = *(const uint2*)(rowp + 4);
    uint4v u = {lo.x, lo.y, hi.x, hi.y};
    return __builtin_bit_cast(bf16x8, u);
}

// ---------------------------------------------------------------------------
// Kernel A: qkv projection via MFMA (unchanged from round 9).
// grid (128, 2, 3), block 256.
// ---------------------------------------------------------------------------
__global__ void __launch_bounds__(256)
qkv_mfma(const float* __restrict__ x, const float* __restrict__ w,
         bf16* __restrict__ qt, bf16* __restrict__ kt, bf16* __restrict__ vt) {
    int tok0 = blockIdx.x * 32;
    int b    = blockIdx.y;
    int z    = blockIdx.z;          // 0=q, 1=k, 2=v
    __shared__ unsigned short xs[128][32];
    __shared__ unsigned short wl[128][132];
    {
        int c = threadIdx.x >> 1, hf = threadIdx.x & 1;
        const float4* x4 = (const float4*)(x + (size_t)b * (128 * N_TOK) +
                                           (size_t)c * N_TOK + tok0 + hf * 16);
        float4 a = x4[0], bb = x4[1], cc = x4[2], dd = x4[3];
        unsigned* dst = (unsigned*)&xs[c][hf * 16];
        dst[0] = pack2(a.x, a.y);   dst[1] = pack2(a.z, a.w);
        dst[2] = pack2(bb.x, bb.y); dst[3] = pack2(bb.z, bb.w);
        dst[4] = pack2(cc.x, cc.y); dst[5] = pack2(cc.z, cc.w);
        dst[6] = pack2(dd.x, dd.y); dst[7] = pack2(dd.z, dd.w);
    }
    {
        float sc = (z == 0) ? SCALE_L2E : 1.0f;
        const float4* wb4 = (const float4*)(w + (size_t)z * 128 * 128);
#pragma unroll
        for (int s = 0; s < 16; ++s) {
            int i4 = threadIdx.x + s * 256;
            int o  = i4 >> 5, c4 = (i4 & 31) * 4;
            float4 wv4 = wb4[i4];
            *(uint2*)&wl[o][c4] = make_uint2(pack2(wv4.x * sc, wv4.y * sc),
                                             pack2(wv4.z * sc, wv4.w * sc));
        }
    }
    __syncthreads();
    int lane = threadIdx.x & 63, wv = threadIdx.x >> 6;
    int i = lane & 31, hl = lane >> 5;

    bf16x8 xf[8], wf[8];
#pragma unroll
    for (int kb = 0; kb < 8; ++kb) {
        bf16x8 f;
#pragma unroll
        for (int e = 0; e < 8; ++e) f[e] = us2bf(xs[kb * 16 + hl * 8 + e][i]);
        xf[kb] = f;
        wf[kb] = ldw(&wl[wv * 32 + i][kb * 16 + hl * 8]);
    }

    f32x16 D;
#pragma unroll
    for (int r = 0; r < 16; ++r) D[r] = 0.f;

    if (z < 2) {
#pragma unroll
        for (int kb = 0; kb < 8; ++kb)
            D = __builtin_amdgcn_mfma_f32_32x32x16_bf16(xf[kb], wf[kb], D, 0, 0, 0);
        bf16* base = (z == 0) ? qt : kt;
        unsigned short* dst = (unsigned short*)(base + ((size_t)(b * 4 + wv) * N_TOK + tok0) * 32);
#pragma unroll
        for (int r = 0; r < 16; ++r) {
            int tr = (r & 3) + 8 * (r >> 2) + 4 * hl;
            dst[tr * 32 + i] = f2b(D[r]);
        }
    } else {
#pragma unroll
        for (int kb = 0; kb < 8; ++kb)
            D = __builtin_amdgcn_mfma_f32_32x32x16_bf16(wf[kb], xf[kb], D, 0, 0, 0);
        unsigned short* dst = (unsigned short*)(vt + (size_t)(b * 4 + wv) * (32 * N_TOK) + tok0);
#pragma unroll
        for (int r = 0; r < 16; ++r) {
            int dr = (r & 3) + 8 * (r >> 2) + 4 * hl;
            dst[(size_t)dr * N_TOK + i] = f2b(D[r]);
        }
    }
}

// ---------------------------------------------------------------------------
// Kernel B: MFMA flash attention. 512 blocks x 256 thr (2 blocks/CU => two
// independent barrier domains per CU). Block = 4 waves = 2 qtiles x 2
// key-halves, 64 queries, all 4096 keys. 4 LDS K/V buffers, ONE barrier per
// 2 chunks (128 keys); paired-chunk compute gives 2 independent MFMA chains
// per interval. l on the MFMA pipe via Ol = mfma(ones, P, Ol).
// grid 512: bh = bid&7 (XCD-locked), g = bid>>3. block 256.
// ---------------------------------------------------------------------------
__global__ void __launch_bounds__(256)
attn_mfma(const bf16* __restrict__ qt, const bf16* __restrict__ kt,
          const bf16* __restrict__ vt, bf16* __restrict__ ao) {
    int bid  = blockIdx.x;
    int bh   = bid & 7;                      // XCD x owns bh x (K/V L2-resident)
    int g    = bid >> 3;                     // 64-query group
    int tid  = threadIdx.x;
    int lane = tid & 63, wv = tid >> 6;
    int qtl  = wv >> 1;                      // 0..1
    int kh   = wv & 1;                       // key half of each chunk
    int i    = lane & 31, hl = lane >> 5;

    __shared__ uint4v lds[4][512];           // 4 buffers x (256 K | 256 V) 16B units

    const bf16* qb = qt + (size_t)bh * (N_TOK * 32) + (size_t)(g * 64 + qtl * 32) * 32;
    const bf16* kb = kt + (size_t)bh * (N_TOK * 32);
    const bf16* vb = vt + (size_t)bh * (32 * N_TOK);

    bf16x8 q1 = ld8(qb + i * 32 + hl * 8);
    bf16x8 q2 = ld8(qb + i * 32 + 16 + hl * 8);

    bf16x8 ones;
#pragma unroll
    for (int e = 0; e < 8; ++e) ones[e] = us2bf(0x3F80);

    f32x16 O, Ol, Z;
#pragma unroll
    for (int r = 0; r < 16; ++r) { O[r] = 0.f; Ol[r] = 0.f; Z[r] = 0.f; }

    // staging: each thread stages 1 K unit + 1 V unit per chunk
    int u = tid;
    int kgoff = ((u >> 7) * 32 + (u & 31)) * 32 + ((u >> 6) & 1) * 16 + ((u >> 5) & 1) * 8;
    int vgoff = (u >> 3) * N_TOK + (u & 7) * 8;
    int ldstK = u;
    int ldstV = 256 + (u & 7) * 32 + (((u >> 3) + (u & 7)) & 31);

    // fragment read indices (lane-linear; V rotation-swizzled)
    int kidx1 = kh * 128 + lane, kidx2 = kidx1 + 64;
    int cA = kh * 4 + hl,     vidx1 = 256 + cA * 32 + ((i + cA) & 31);
    int cB = kh * 4 + 2 + hl, vidx2 = 256 + cB * 32 + ((i + cB) & 31);

    // prologue: stage chunks 0,1
    lds[0][ldstK] = *(const uint4v*)(kb + kgoff);
    lds[0][ldstV] = *(const uint4v*)(vb + vgoff);
    lds[1][ldstK] = *(const uint4v*)(kb + (size_t)64 * 32 + kgoff);
    lds[1][ldstV] = *(const uint4v*)(vb + 64 + vgoff);
    __syncthreads();

    for (int t = 0; t < 32; ++t) {
        uint4v nk0, nv0, nk1, nv1;
        if (t < 31) {   // issue next interval's 4 loads early (hide L2 latency)
            size_t j0 = (size_t)(2 * t + 2) * 64;
            nk0 = *(const uint4v*)(kb + j0 * 32 + kgoff);
            nv0 = *(const uint4v*)(vb + j0 + vgoff);
            nk1 = *(const uint4v*)(kb + (j0 + 64) * 32 + kgoff);
            nv1 = *(const uint4v*)(vb + (j0 + 64) + vgoff);
        }
        const uint4v* LA = lds[(2 * t) & 3];
        const uint4v* LB = lds[(2 * t + 1) & 3];

        // both S chains issued back-to-back (independent => ILP)
        bf16x8 kaA1 = __builtin_bit_cast(bf16x8, LA[kidx1]);
        bf16x8 kaA2 = __builtin_bit_cast(bf16x8, LA[kidx2]);
        f32x16 SA = __builtin_amdgcn_mfma_f32_32x32x16_bf16(kaA1, q1, Z, 0, 0, 0);
        SA = __builtin_amdgcn_mfma_f32_32x32x16_bf16(kaA2, q2, SA, 0, 0, 0);
        bf16x8 kaB1 = __builtin_bit_cast(bf16x8, LB[kidx1]);
        bf16x8 kaB2 = __builtin_bit_cast(bf16x8, LB[kidx2]);
        f32x16 SB = __builtin_amdgcn_mfma_f32_32x32x16_bf16(kaB1, q1, Z, 0, 0, 0);
        SB = __builtin_amdgcn_mfma_f32_32x32x16_bf16(kaB2, q2, SB, 0, 0, 0);

        bf16x8 vaA1 = __builtin_bit_cast(bf16x8, LA[vidx1]);
        bf16x8 vaA2 = __builtin_bit_cast(bf16x8, LA[vidx2]);
        bf16x8 vaB1 = __builtin_bit_cast(bf16x8, LB[vidx1]);
        bf16x8 vaB2 = __builtin_bit_cast(bf16x8, LB[vidx2]);

        // ---- chunk A: softmax + PV ----
        {
            float p[16];
#pragma unroll
            for (int r = 0; r < 16; ++r) p[r] = __builtin_amdgcn_exp2f(SA[r]);
            unsigned pk0 = pack2(p[0], p[1]),   pk1 = pack2(p[2], p[3]);
            unsigned pk2 = pack2(p[4], p[5]),   pk3 = pack2(p[6], p[7]);
            unsigned pk4 = pack2(p[8], p[9]),   pk5 = pack2(p[10], p[11]);
            unsigned pk6 = pack2(p[12], p[13]), pk7 = pack2(p[14], p[15]);
            i32x2 t1 = __builtin_amdgcn_permlane32_swap((int)pk0, (int)pk2, false, false);
            i32x2 t2 = __builtin_amdgcn_permlane32_swap((int)pk1, (int)pk3, false, false);
            i32x2 t3 = __builtin_amdgcn_permlane32_swap((int)pk4, (int)pk6, false, false);
            i32x2 t4 = __builtin_amdgcn_permlane32_swap((int)pk5, (int)pk7, false, false);
            uint4v B1u = {(unsigned)t1.x, (unsigned)t2.x, (unsigned)t1.y, (unsigned)t2.y};
            uint4v B2u = {(unsigned)t3.x, (unsigned)t4.x, (unsigned)t3.y, (unsigned)t4.y};
            bf16x8 B1 = __builtin_bit_cast(bf16x8, B1u);
            bf16x8 B2 = __builtin_bit_cast(bf16x8, B2u);
            O  = __builtin_amdgcn_mfma_f32_32x32x16_bf16(vaA1, B1, O, 0, 0, 0);
            O  = __builtin_amdgcn_mfma_f32_32x32x16_bf16(vaA2, B2, O, 0, 0, 0);
            Ol = __builtin_amdgcn_mfma_f32_32x32x16_bf16(ones, B1, Ol, 0, 0, 0);
            Ol = __builtin_amdgcn_mfma_f32_32x32x16_bf16(ones, B2, Ol, 0, 0, 0);
        }
        // ---- chunk B: softmax + PV ----
        {
            float p[16];
#pragma unroll
            for (int r = 0; r < 16; ++r) p[r] = __builtin_amdgcn_exp2f(SB[r]);
            unsigned pk0 = pack2(p[0], p[1]),   pk1 = pack2(p[2], p[3]);
            unsigned pk2 = pack2(p[4], p[5]),   pk3 = pack2(p[6], p[7]);
            unsigned pk4 = pack2(p[8], p[9]),   pk5 = pack2(p[10], p[11]);
            unsigned pk6 = pack2(p[12], p[13]), pk7 = pack2(p[14], p[15]);
            i32x2 t1 = __builtin_amdgcn_permlane32_swap((int)pk0, (int)pk2, false, false);
            i32x2 t2 = __builtin_amdgcn_permlane32_swap((int)pk1, (int)pk3, false, false);
            i32x2 t3 = __builtin_amdgcn_permlane32_swap((int)pk4, (int)pk6, false, false);
            i32x2 t4 = __builtin_amdgcn_permlane32_swap((int)pk5, (int)pk7, false, false);
            uint4v B1u = {(unsigned)t1.x, (unsigned)t2.x, (unsigned)t1.y, (unsigned)t2.y};
            uint4v B2u = {(unsigned)t3.x, (unsigned)t4.x, (unsigned)t3.y, (unsigned)t4.y};
            bf16x8 B1 = __builtin_bit_cast(bf16x8, B1u);
            bf16x8 B2 = __builtin_bit_cast(bf16x8, B2u);
            O  = __builtin_amdgcn_mfma_f32_32x32x16_bf16(vaB1, B1, O, 0, 0, 0);
            O  = __builtin_amdgcn_mfma_f32_32x32x16_bf16(vaB2, B2, O, 0, 0, 0);
            Ol = __builtin_amdgcn_mfma_f32_32x32x16_bf16(ones, B1, Ol, 0, 0, 0);
            Ol = __builtin_amdgcn_mfma_f32_32x32x16_bf16(ones, B2, Ol, 0, 0, 0);
        }

        if (t < 31) {   // publish next interval's chunks; barrier releases them
            lds[(2 * t + 2) & 3][ldstK] = nk0;
            lds[(2 * t + 2) & 3][ldstV] = nv0;
            lds[(2 * t + 3) & 3][ldstK] = nk1;
            lds[(2 * t + 3) & 3][ldstV] = nv1;
        }
        __syncthreads();
    }

    // ---- combine the 2 key-half partials per qtile (Ol[0] = wave's l) ----
    float* fb = (float*)lds;
    float l = Ol[0];
    if (kh == 1) {
#pragma unroll
        for (int r = 0; r < 16; ++r) fb[qtl * 1024 + r * 64 + lane] = O[r];
        fb[2048 + qtl * 64 + lane] = l;
    }
    __syncthreads();
    if (kh == 0) {
        float lt  = l + fb[2048 + qtl * 64 + lane];
        float inv = 1.f / lt;
        unsigned short* aop = (unsigned short*)(ao + (size_t)bh * (32 * N_TOK) + g * 64 + qtl * 32);
#pragma unroll
        for (int r = 0; r < 16; ++r) {
            float s = O[r] + fb[qtl * 1024 + r * 64 + lane];
            int d = (r & 3) + 8 * (r >> 2) + 4 * hl;
            aop[(size_t)d * N_TOK + i] = f2b(s * inv);
        }
    }
}

// ---------------------------------------------------------------------------
// Kernel C: out projection via MFMA + bias + residual (unchanged from round 9).
// grid (128, 2), block 256.
// ---------------------------------------------------------------------------
__global__ void __launch_bounds__(256)
out_mfma(const bf16* __restrict__ ao, const float* __restrict__ w,
         const float* __restrict__ bias, const float* __restrict__ x,
         float* __restrict__ out) {
    int tok0 = blockIdx.x * 32;
    int b    = blockIdx.y;
    __shared__ unsigned short as_[128][32];
    __shared__ unsigned short wl[128][132];
    {
        int c = threadIdx.x >> 1, hf = threadIdx.x & 1;
        const uint4v* src = (const uint4v*)(ao + (size_t)b * (128 * N_TOK) +
                                            (size_t)c * N_TOK + tok0 + hf * 16);
        uint4v v0 = src[0], v1 = src[1];
        uint4v* dst = (uint4v*)&as_[c][hf * 16];
        dst[0] = v0; dst[1] = v1;
    }
    {
        const float4* wb4 = (const float4*)w;
#pragma unroll
        for (int s = 0; s < 16; ++s) {
            int i4 = threadIdx.x + s * 256;
            int o  = i4 >> 5, c4 = (i4 & 31) * 4;
            float4 wv4 = wb4[i4];
            *(uint2*)&wl[o][c4] = make_uint2(pack2(wv4.x, wv4.y), pack2(wv4.z, wv4.w));
        }
    }
    __syncthreads();
    int lane = threadIdx.x & 63, wv = threadIdx.x >> 6;
    int i = lane & 31, hl = lane >> 5;

    bf16x8 af[8], wf[8];
#pragma unroll
    for (int kb = 0; kb < 8; ++kb) {
        bf16x8 f;
#pragma unroll
        for (int e = 0; e < 8; ++e) f[e] = us2bf(as_[kb * 16 + hl * 8 + e][i]);
        af[kb] = f;
        wf[kb] = ldw(&wl[wv * 32 + i][kb * 16 + hl * 8]);
    }

    f32x16 D;
#pragma unroll
    for (int r = 0; r < 16; ++r) D[r] = 0.f;
#pragma unroll
    for (int kb = 0; kb < 8; ++kb)
        D = __builtin_amdgcn_mfma_f32_32x32x16_bf16(wf[kb], af[kb], D, 0, 0, 0);

#pragma unroll
    for (int r = 0; r < 16; ++r) {
        int o_r = wv * 32 + (r & 3) + 8 * (r >> 2) + 4 * hl;
        size_t idx = ((size_t)b * 128 + o_r) * N_TOK + tok0 + i;
        out[idx] = D[r] + bias[o_r] + x[idx];
    }
}

// ---------------------------------------------------------------------------
extern "C" void kernel_launch(void* const* d_in, const int* in_sizes, int n_in,
                              void* d_out, int out_size, void* d_ws, size_t ws_size,
                              hipStream_t stream) {
    const float* x     = (const float*)d_in[0];
    const float* w_qkv = (const float*)d_in[1];
    const float* w_out = (const float*)d_in[2];
    const float* b_out = (const float*)d_in[3];
    float* out = (float*)d_out;

    bf16* qt = (bf16*)d_ws;                          // [8][4096][32] bf16 = 2 MB
    bf16* kt = qt + (size_t)8 * N_TOK * 32;          // [8][4096][32] bf16 = 2 MB
    bf16* vt = kt + (size_t)8 * N_TOK * 32;          // [8][32][4096] bf16 = 2 MB
    bf16* ao = vt + (size_t)8 * N_TOK * 32;          // [2][128][4096] bf16 = 2 MB

    qkv_mfma <<<dim3(128, 2, 3), 256, 0, stream>>>(x, w_qkv, qt, kt, vt);
    attn_mfma<<<dim3(512), 256, 0, stream>>>(qt, kt, vt, ao);
    out_mfma <<<dim3(128, 2), 256, 0, stream>>>(ao, w_out, b_out, x, out);
}